// Round 2
// baseline (175.104 us; speedup 1.0000x reference)
//
#include <hip/hip_runtime.h>

// Problem constants (fixed by setup_inputs)
#define BSZ   4
#define CCH   320
#define HH    96
#define WW    192
#define NHEAD 16
#define NC    20          // channels per group = 320/16
#define DMAX  64
#define HWSZ  (HH * WW)
#define NS    128         // slots per parity ((WW + DMAX) / 2)
#define YPB   2           // rows per block

// Block = (b, g, y-pair). 192 threads: thread -> (row r = tid/96, i = tid%96),
// covering x0 = 2i and x0+1. rf row staged in LDS, left-padded by DMAX zeros,
// PARITY-SPLIT so the sliding-window reads (slot = 2i - d, uniform parity per
// step) are lane-stride-20-float -> conflict-free ds_read_b128.
__global__ __launch_bounds__(192) void gwc_kernel(const float* __restrict__ lf,
                                                  const float* __restrict__ rf,
                                                  float* __restrict__ out) {
    // lds[row][parity][slot][ch] ; slot sp (=x+64) -> [sp&1][sp>>1]
    __shared__ __align__(16) float lds[YPB][2][NS][NC];   // 40960 B

    const int tid = threadIdx.x;
    const int r   = tid / 96;         // row within block
    const int i   = tid % 96;         // x-pair index; x0 = 2i
    int bid = blockIdx.x;
    const int yp = bid % (HH / YPB); bid /= (HH / YPB);
    const int g  = bid % NHEAD;      bid /= NHEAD;
    const int b  = bid;
    const int y  = yp * YPB + r;

    // zero the left pad: for each of the 4 [NS][NC] sub-arrays, slots k<32.
    {
        float* base = (float*)lds;
        for (int idx = tid; idx < 4 * 32 * NC; idx += 192) {
            const int q   = idx / (32 * NC);      // which (row,parity) block
            const int off = idx % (32 * NC);      // within first 32 slots
            base[q * (NS * NC) + off] = 0.0f;
        }
    }

    const size_t inoff = ((size_t)(b * CCH + g * NC) * HH + y) * WW + 2 * i;
    const float* lfp = lf + inoff;
    const float* rfp = rf + inoff;

    float4 l0[5], l1[5];   // lf channel packs for x0, x0+1
#pragma unroll
    for (int j = 0; j < 5; ++j) {
        const float2 a0 = *(const float2*)(lfp + (size_t)(4 * j + 0) * HWSZ);
        const float2 a1 = *(const float2*)(lfp + (size_t)(4 * j + 1) * HWSZ);
        const float2 a2 = *(const float2*)(lfp + (size_t)(4 * j + 2) * HWSZ);
        const float2 a3 = *(const float2*)(lfp + (size_t)(4 * j + 3) * HWSZ);
        l0[j] = make_float4(a0.x, a1.x, a2.x, a3.x);
        l1[j] = make_float4(a0.y, a1.y, a2.y, a3.y);
        const float2 r0 = *(const float2*)(rfp + (size_t)(4 * j + 0) * HWSZ);
        const float2 r1 = *(const float2*)(rfp + (size_t)(4 * j + 1) * HWSZ);
        const float2 r2 = *(const float2*)(rfp + (size_t)(4 * j + 2) * HWSZ);
        const float2 r3 = *(const float2*)(rfp + (size_t)(4 * j + 3) * HWSZ);
        // slot 2i+64 (parity 0, k=i+32) gets .x comps; slot 2i+65 (parity 1) .y
        ((float4*)&lds[r][0][i + 32][0])[j] = make_float4(r0.x, r1.x, r2.x, r3.x);
        ((float4*)&lds[r][1][i + 32][0])[j] = make_float4(r0.y, r1.y, r2.y, r3.y);
    }
    __syncthreads();

    const float4* E = (const float4*)&lds[r][0][0][0];  // 5 float4 per slot
    const float4* O = (const float4*)&lds[r][1][0][0];

    float4 A[5], Bv[5];
#pragma unroll
    for (int j = 0; j < 5; ++j) {
        A[j]  = E[(i + 32) * 5 + j];   // slot 2i+64
        Bv[j] = O[(i + 32) * 5 + j];   // slot 2i+65
    }

    float* op = out + (size_t)(b * NHEAD + g) * DMAX * HWSZ + (size_t)y * WW + 2 * i;
    const float scale = 0.22360679774997896f;  // 1/sqrt(20)

#pragma unroll 2
    for (int t = 0; t < 32; ++t) {
        float4 An[5], Bn[5];
        const int k = (i + 31 - t) * 5;
#pragma unroll
        for (int j = 0; j < 5; ++j) { Bn[j] = O[k + j]; An[j] = E[k + j]; }

        // d = 2t : x0 uses slot 2i+64-2t (= A), x0+1 uses 2i+65-2t (= Bv)
        float s0 = 0.0f, s1 = 0.0f;
#pragma unroll
        for (int j = 0; j < 5; ++j) {
            s0 += l0[j].x * A[j].x  + l0[j].y * A[j].y  + l0[j].z * A[j].z  + l0[j].w * A[j].w;
            s1 += l1[j].x * Bv[j].x + l1[j].y * Bv[j].y + l1[j].z * Bv[j].z + l1[j].w * Bv[j].w;
        }
        *(float2*)(op + (size_t)(2 * t) * HWSZ) = make_float2(s0 * scale, s1 * scale);

        // d = 2t+1 : x0 uses slot 2i+63-2t (= Bn), x0+1 uses 2i+64-2t (= A)
        s0 = 0.0f; s1 = 0.0f;
#pragma unroll
        for (int j = 0; j < 5; ++j) {
            s0 += l0[j].x * Bn[j].x + l0[j].y * Bn[j].y + l0[j].z * Bn[j].z + l0[j].w * Bn[j].w;
            s1 += l1[j].x * A[j].x  + l1[j].y * A[j].y  + l1[j].z * A[j].z  + l1[j].w * A[j].w;
        }
        *(float2*)(op + (size_t)(2 * t + 1) * HWSZ) = make_float2(s0 * scale, s1 * scale);

#pragma unroll
        for (int j = 0; j < 5; ++j) { A[j] = An[j]; Bv[j] = Bn[j]; }
    }
}

extern "C" void kernel_launch(void* const* d_in, const int* in_sizes, int n_in,
                              void* d_out, int out_size, void* d_ws, size_t ws_size,
                              hipStream_t stream) {
    const float* lf = (const float*)d_in[0];
    const float* rf = (const float*)d_in[1];
    float* out = (float*)d_out;

    const int grid = BSZ * NHEAD * (HH / YPB);  // 3072 blocks
    gwc_kernel<<<grid, 192, 0, stream>>>(lf, rf, out);
}

// Round 3
// 169.295 us; speedup vs baseline: 1.0343x; 1.0343x over previous
//
#include <hip/hip_runtime.h>

// Problem constants (fixed by setup_inputs)
#define BSZ   4
#define CCH   320
#define HH    96
#define WW    192
#define NHEAD 16
#define NC    20          // channels per group = 320/16
#define DMAX  64
#define HWSZ  (HH * WW)

// 20-term dot of lf channel-pack L[5] with window slot W[5] (two partial chains for ILP)
__device__ __forceinline__ float dot20(const float4* L, const float4* W) {
    float sa = 0.f, sb = 0.f;
#pragma unroll
    for (int j = 0; j < 5; ++j) {
        float& s = (j & 1) ? sb : sa;
        s = fmaf(L[j].x, W[j].x, s);
        s = fmaf(L[j].y, W[j].y, s);
        s = fmaf(L[j].z, W[j].z, s);
        s = fmaf(L[j].w, W[j].w, s);
    }
    return sa + sb;
}

// One 64-thread block per (b,g,y) row. Lane i owns x = 3i..3i+2.
// rf row in LDS mod-3 interleaved: x stored at lds[x%3][x/3] (20 ch = 5 float4).
// Register ring A/B/C holds 3 slots; each d-step prefetches ONE new slot
// (issued a full step before first use) and emits 3 outputs.
// No zero pad: reads clamp to index 0; outputs with x<d are masked to 0.
__global__ __launch_bounds__(64, 3) void gwc_kernel(const float* __restrict__ lf,
                                                    const float* __restrict__ rf,
                                                    float* __restrict__ out) {
    __shared__ float4 lds[3][64][5];   // 15360 B

    const int i = threadIdx.x;         // 0..63 ; x0 = 3i
    int bid = blockIdx.x;
    const int y = bid % HH;  bid /= HH;
    const int g = bid % NHEAD; bid /= NHEAD;
    const int b = bid;
    const int x0 = 3 * i;

    const float* lp = lf + ((size_t)(b * CCH + g * NC) * HH + y) * WW + x0;
    const float* rp = rf + ((size_t)(b * CCH + g * NC) * HH + y) * WW + x0;

    float4 L0[5], L1[5], L2[5];        // lf for x0, x0+1, x0+2 (ch-packed)

    // Stage: scalar loads (lane-stride 12 B, all cachelines covered), rf -> LDS.
#pragma unroll
    for (int j = 0; j < 5; ++j) {
        float la[3][4], ra[3][4];
#pragma unroll
        for (int cc = 0; cc < 4; ++cc) {
            const size_t o = (size_t)(4 * j + cc) * HWSZ;
#pragma unroll
            for (int k = 0; k < 3; ++k) {
                la[k][cc] = lp[o + k];
                ra[k][cc] = rp[o + k];
            }
        }
        L0[j] = make_float4(la[0][0], la[0][1], la[0][2], la[0][3]);
        L1[j] = make_float4(la[1][0], la[1][1], la[1][2], la[1][3]);
        L2[j] = make_float4(la[2][0], la[2][1], la[2][2], la[2][3]);
        lds[0][i][j] = make_float4(ra[0][0], ra[0][1], ra[0][2], ra[0][3]);
        lds[1][i][j] = make_float4(ra[1][0], ra[1][1], ra[1][2], ra[1][3]);
        lds[2][i][j] = make_float4(ra[2][0], ra[2][1], ra[2][2], ra[2][3]);
    }
    __syncthreads();

    // Window init: slots x0, x0+1, x0+2 (d=0 window)
    float4 A[5], B[5], C[5];
#pragma unroll
    for (int j = 0; j < 5; ++j) {
        A[j] = lds[0][i][j];
        B[j] = lds[1][i][j];
        C[j] = lds[2][i][j];
    }

    float* op = out + (size_t)(b * NHEAD + g) * DMAX * HWSZ + (size_t)y * WW + x0;
    const float scale = 0.22360679774997896f;   // 1/sqrt(20)
    int ii = (i > 0) ? (i - 1) : 0;             // clamped sub-array index, shared by all 3 residues
    int d = 0;

    // PN = newest slot (x0-d), PM = mid (x0+1-d), PO = oldest (x0+2-d; dies this step).
    // Prefetch for step d+1 lands in PO right after its last use -> ~1 full step of cover.
#define GWC_STEP(PN, PM, PO, RR, PF)                                        \
    {                                                                       \
        const float s2 = dot20(L2, PO);                                     \
        if (PF) {                                                           \
            PO[0] = lds[RR][ii][0]; PO[1] = lds[RR][ii][1];                 \
            PO[2] = lds[RR][ii][2]; PO[3] = lds[RR][ii][3];                 \
            PO[4] = lds[RR][ii][4];                                         \
        }                                                                   \
        const float s1 = dot20(L1, PM);                                     \
        const float s0 = dot20(L0, PN);                                     \
        op[0] = (x0     >= d) ? s0 * scale : 0.f;                           \
        op[1] = (x0 + 1 >= d) ? s1 * scale : 0.f;                           \
        op[2] = (x0 + 2 >= d) ? s2 * scale : 0.f;                           \
        op += HWSZ; ++d;                                                    \
    }

    for (int to = 0; to < 21; ++to) {
        GWC_STEP(A, B, C, 2, 1)
        GWC_STEP(C, A, B, 1, 1)
        GWC_STEP(B, C, A, 0, 1)
        ii = (ii > 0) ? (ii - 1) : 0;
    }
    GWC_STEP(A, B, C, 2, 0)   // d = 63, no prefetch
#undef GWC_STEP
}

extern "C" void kernel_launch(void* const* d_in, const int* in_sizes, int n_in,
                              void* d_out, int out_size, void* d_ws, size_t ws_size,
                              hipStream_t stream) {
    const float* lf = (const float*)d_in[0];
    const float* rf = (const float*)d_in[1];
    float* out = (float*)d_out;

    const int grid = BSZ * NHEAD * HH;   // 6144 blocks, one row each
    gwc_kernel<<<grid, 64, 0, stream>>>(lf, rf, out);
}